// Round 3
// baseline (4263.157 us; speedup 1.0000x reference)
//
#include <hip/hip_runtime.h>
#include <hip/hip_bf16.h>

#define NN   100000
#define NE   1600000
#define FIN  256
#define HID  32
#define OUTD 16

// ---- workspace layout (float offsets) ----
#define OFF_FLAG  0               // [0]=is64, [1]=isf32
#define OFF_DEG   64
#define OFF_ACC1  (OFF_DEG + NN)          // 100064
#define OFF_ACC2  (OFF_ACC1 + NN*HID)     // 3300064
#define OFF_DINV  (OFF_ACC2 + NN*OUTD)    // 4900064
#define OFF_NORM  (OFF_DINV + NN)         // 5000064
#define OFF_H1    (OFF_NORM + NE)         // 6600064
#define OFF_P2    (OFF_H1 + NN*HID)       // 9800064
#define ZERO_COUNT (NN + NN*HID + NN*OUTD) // deg+acc1+acc2 contiguous = 4,900,000 floats

__device__ __forceinline__ float bf2f(unsigned short u) {
  union { unsigned int i; float f; } v; v.i = ((unsigned int)u) << 16; return v.f;
}
__device__ __forceinline__ unsigned short f2bf(float f) {
  union { float f; unsigned int i; } v; v.f = f;
  unsigned int x = v.i;
  return (unsigned short)((x + 0x7fffu + ((x >> 16) & 1u)) >> 16); // RNE
}
__device__ __forceinline__ int eidx(const int* __restrict__ ei, int pos, int is64) {
  return is64 ? ei[2 * pos] : ei[pos];
}
// scalar float load from possibly-bf16 buffer
__device__ __forceinline__ float ldf(const void* p, long long i, int isf32) {
  return isf32 ? ((const float*)p)[i] : bf2f(((const unsigned short*)p)[i]);
}

// ---- 0: zero fill ----
__global__ __launch_bounds__(256) void zero_kernel(float* __restrict__ p, int n) {
  int stride = gridDim.x * blockDim.x;
  for (int i = blockIdx.x * blockDim.x + threadIdx.x; i < n; i += stride) p[i] = 0.f;
}

// ---- 1: detect (a) int64 vs int32 edge_index, (b) f32 vs bf16 floats ----
// (b): even-index ushorts of x. bf16 N(0,1): exponent field in [100,140]
// (P(outside)~1e-8). f32: even ushorts are low mantissa bits, uniform ->
// ~84% outside. 1024 samples, threshold 100.
__global__ __launch_bounds__(256) void detect_kernel(const int* __restrict__ ei,
    const unsigned short* __restrict__ xu, int* __restrict__ flags) {
  __shared__ int any, cnt;
  if (threadIdx.x == 0) { any = 0; cnt = 0; }
  __syncthreads();
  int local = 0, c = 0;
  for (int i = threadIdx.x; i < 2048; i += 256) local |= ei[2 * i + 1];
  for (int i = threadIdx.x; i < 1024; i += 256) {
    unsigned int e = (xu[2 * i] >> 7) & 0xFF;
    c += (e < 100 || e > 140) ? 1 : 0;
  }
  if (local) atomicOr(&any, 1);
  atomicAdd(&cnt, c);
  __syncthreads();
  if (threadIdx.x == 0) {
    flags[0] = (any == 0) ? 1 : 0;   // 1 => int64 layout
    flags[1] = (cnt > 100) ? 1 : 0;  // 1 => f32 floats
  }
}

// ---- 2: degree[c] += w  (self-loop +1 added in dinv kernel) ----
__global__ __launch_bounds__(256) void degree_kernel(const int* __restrict__ ei,
    const void* __restrict__ ew, float* __restrict__ deg,
    const int* __restrict__ flags) {
  int e = blockIdx.x * 256 + threadIdx.x;
  if (e >= NE) return;
  int c = eidx(ei, NE + e, flags[0]);
  atomicAdd(deg + c, ldf(ew, e, flags[1]));
}

// ---- 3: dinv ----
__global__ __launch_bounds__(256) void dinv_kernel(const float* __restrict__ deg,
                                                   float* __restrict__ dinv) {
  int i = blockIdx.x * 256 + threadIdx.x;
  if (i >= NN) return;
  float d = deg[i] + 1.0f;  // self-loop weight 1
  dinv[i] = (d > 0.f) ? rsqrtf(d) : 0.f;
}

// ---- 4: per-edge norm ----
__global__ __launch_bounds__(256) void norm_kernel(const int* __restrict__ ei,
    const void* __restrict__ ew, const float* __restrict__ dinv,
    float* __restrict__ norm, const int* __restrict__ flags) {
  int e = blockIdx.x * 256 + threadIdx.x;
  if (e >= NE) return;
  int is64 = flags[0];
  int r = eidx(ei, e, is64);
  int c = eidx(ei, NE + e, is64);
  norm[e] = dinv[r] * ldf(ew, e, flags[1]) * dinv[c];
}

// ---- 5: h1 = x @ W1   [NN,256]x[256,32] ----
// 256 threads/block, 128 rows/block; thread: 2 cols x 8 rows
__global__ __launch_bounds__(256) void gemm1_kernel(const void* __restrict__ x,
    const void* __restrict__ W1, float* __restrict__ h1,
    const int* __restrict__ flags) {
  __shared__ float wlds[FIN][HID];   // 32 KB
  __shared__ float xs[32][132];      // 16.5 KB, transposed [k][row]
  int t = threadIdx.x;
  int rb = blockIdx.x * 128;
  int isf32 = flags[1];

  // load W1 -> LDS (thread t loads row t: 32 values)
  if (isf32) {
    const float* wrow = (const float*)W1 + t * HID;
    #pragma unroll
    for (int jj = 0; jj < HID; jj += 4)
      *(float4*)&wlds[t][jj] = *((const float4*)(wrow + jj));
  } else {
    const unsigned short* wrow = (const unsigned short*)W1 + t * HID;
    #pragma unroll
    for (int jj = 0; jj < HID; jj += 8) {
      uint4 pk = *((const uint4*)(wrow + jj));
      const unsigned short* pu = (const unsigned short*)&pk;
      #pragma unroll
      for (int q = 0; q < 8; q++) wlds[t][jj + q] = bf2f(pu[q]);
    }
  }

  int j0 = (t & 15) * 2;
  int rgrp = t >> 4;
  int r0 = rgrp * 8;
  float acc[8][2];
  #pragma unroll
  for (int i = 0; i < 8; i++) { acc[i][0] = 0.f; acc[i][1] = 0.f; }

  for (int kc = 0; kc < FIN; kc += 32) {
    __syncthreads();
    // stage x chunk transposed: thread t: row rr=t>>1, 16 k starting at (t&1)*16
    {
      int rr = t >> 1;
      int kk0 = (t & 1) * 16;
      int grow = rb + rr;
      if (grow < NN) {
        if (isf32) {
          const float* xp = (const float*)x + (long long)grow * FIN + kc + kk0;
          #pragma unroll
          for (int q4 = 0; q4 < 4; q4++) {
            float4 p = ((const float4*)xp)[q4];
            xs[kk0 + q4 * 4 + 0][rr] = p.x;
            xs[kk0 + q4 * 4 + 1][rr] = p.y;
            xs[kk0 + q4 * 4 + 2][rr] = p.z;
            xs[kk0 + q4 * 4 + 3][rr] = p.w;
          }
        } else {
          const unsigned short* xp = (const unsigned short*)x + (long long)grow * FIN + kc + kk0;
          uint4 p0 = ((const uint4*)xp)[0];
          uint4 p1 = ((const uint4*)xp)[1];
          const unsigned short* pu = (const unsigned short*)&p0;
          #pragma unroll
          for (int q = 0; q < 8; q++) xs[kk0 + q][rr] = bf2f(pu[q]);
          pu = (const unsigned short*)&p1;
          #pragma unroll
          for (int q = 0; q < 8; q++) xs[kk0 + 8 + q][rr] = bf2f(pu[q]);
        }
      } else {
        #pragma unroll
        for (int q = 0; q < 16; q++) xs[kk0 + q][rr] = 0.f;
      }
    }
    __syncthreads();
    #pragma unroll 8
    for (int kk = 0; kk < 32; kk++) {
      float w0 = wlds[kc + kk][j0];
      float w1 = wlds[kc + kk][j0 + 1];
      const float4* xr = (const float4*)&xs[kk][r0];
      float4 xa = xr[0], xb = xr[1];
      float xv[8] = {xa.x, xa.y, xa.z, xa.w, xb.x, xb.y, xb.z, xb.w};
      #pragma unroll
      for (int i = 0; i < 8; i++) {
        acc[i][0] = fmaf(xv[i], w0, acc[i][0]);
        acc[i][1] = fmaf(xv[i], w1, acc[i][1]);
      }
    }
  }
  #pragma unroll
  for (int i = 0; i < 8; i++) {
    int grow = rb + r0 + i;
    if (grow < NN) {
      float2 v; v.x = acc[i][0]; v.y = acc[i][1];
      *((float2*)(h1 + (long long)grow * HID + j0)) = v;
    }
  }
}

// ---- 6: scatter conv1: acc1[col] += norm[e] * h1[row] (32 cols) ----
__global__ __launch_bounds__(256) void scatter1_kernel(const int* __restrict__ ei,
    const float* __restrict__ norm, const float* __restrict__ h1,
    float* __restrict__ acc1, const int* __restrict__ flags) {
  int e = blockIdx.x * 256 + threadIdx.x;
  if (e >= NE) return;
  int is64 = flags[0];
  int r = eidx(ei, e, is64);
  int c = eidx(ei, NE + e, is64);
  float nw = norm[e];
  const float4* hp = (const float4*)(h1 + (long long)r * HID);
  float* ap = acc1 + (long long)c * HID;
  #pragma unroll
  for (int q = 0; q < 8; q++) {
    float4 v = hp[q];
    atomicAdd(ap + q * 4 + 0, nw * v.x);
    atomicAdd(ap + q * 4 + 1, nw * v.y);
    atomicAdd(ap + q * 4 + 2, nw * v.z);
    atomicAdd(ap + q * 4 + 3, nw * v.w);
  }
}

// ---- 7: self-loop + bias + ReLU + @W2 -> p2  (16 nodes/block, 16 thr/node) ----
__global__ __launch_bounds__(256) void relu_proj2_kernel(const float* __restrict__ acc1,
    const float* __restrict__ h1, const float* __restrict__ dinv,
    const void* __restrict__ b1, const void* __restrict__ W2,
    float* __restrict__ p2, const int* __restrict__ flags) {
  __shared__ float w2lds[HID * OUTD]; // [k][j] flat, 2 KB
  __shared__ float b1l[HID];
  __shared__ float tl[16][33];        // padded
  int t = threadIdx.x;
  int isf32 = flags[1];
  w2lds[2 * t]     = ldf(W2, 2 * t, isf32);
  w2lds[2 * t + 1] = ldf(W2, 2 * t + 1, isf32);
  if (t < HID) b1l[t] = ldf(b1, t, isf32);
  __syncthreads();  // b1l/w2lds read by all threads below

  int i_loc = t >> 4;
  int jj = t & 15;
  int node = blockIdx.x * 16 + i_loc;
  if (node < NN) {
    float di = dinv[node];
    float sl = di * di;
    int k0 = jj * 2;
    float2 a = *(const float2*)(acc1 + (long long)node * HID + k0);
    float2 h = *(const float2*)(h1 + (long long)node * HID + k0);
    tl[i_loc][k0]     = fmaxf(a.x + sl * h.x + b1l[k0], 0.f);
    tl[i_loc][k0 + 1] = fmaxf(a.y + sl * h.y + b1l[k0 + 1], 0.f);
  }
  __syncthreads();
  if (node < NN) {
    float s = 0.f;
    #pragma unroll
    for (int k = 0; k < HID; k++) s = fmaf(tl[i_loc][k], w2lds[k * OUTD + jj], s);
    p2[(long long)node * OUTD + jj] = s;
  }
}

// ---- 8: scatter conv2: acc2[col] += norm[e] * p2[row] (16 cols) ----
__global__ __launch_bounds__(256) void scatter2_kernel(const int* __restrict__ ei,
    const float* __restrict__ norm, const float* __restrict__ p2,
    float* __restrict__ acc2, const int* __restrict__ flags) {
  int e = blockIdx.x * 256 + threadIdx.x;
  if (e >= NE) return;
  int is64 = flags[0];
  int r = eidx(ei, e, is64);
  int c = eidx(ei, NE + e, is64);
  float nw = norm[e];
  const float4* pp = (const float4*)(p2 + (long long)r * OUTD);
  float* ap = acc2 + (long long)c * OUTD;
  #pragma unroll
  for (int q = 0; q < 4; q++) {
    float4 v = pp[q];
    atomicAdd(ap + q * 4 + 0, nw * v.x);
    atomicAdd(ap + q * 4 + 1, nw * v.y);
    atomicAdd(ap + q * 4 + 2, nw * v.z);
    atomicAdd(ap + q * 4 + 3, nw * v.w);
  }
}

// ---- 9: finalize: out = cast(acc2 + dinv^2*p2 + b2) ----
__global__ __launch_bounds__(256) void finalize_kernel(const float* __restrict__ acc2,
    const float* __restrict__ p2, const float* __restrict__ dinv,
    const void* __restrict__ b2, void* __restrict__ out,
    const int* __restrict__ flags) {
  int idx = blockIdx.x * 256 + threadIdx.x;
  if (idx >= NN * OUTD) return;
  int i = idx >> 4;
  int j = idx & 15;
  int isf32 = flags[1];
  float di = dinv[i];
  float v = acc2[idx] + di * di * p2[idx] + ldf(b2, j, isf32);
  if (isf32) ((float*)out)[idx] = v;
  else       ((unsigned short*)out)[idx] = f2bf(v);
}

extern "C" void kernel_launch(void* const* d_in, const int* in_sizes, int n_in,
                              void* d_out, int out_size, void* d_ws, size_t ws_size,
                              hipStream_t stream) {
  const void* x  = d_in[0];
  const int* ei  = (const int*)d_in[1];
  const void* ew = d_in[2];
  const void* W1 = d_in[3];
  const void* b1 = d_in[4];
  const void* W2 = d_in[5];
  const void* b2 = d_in[6];
  float* ws = (float*)d_ws;
  int* flags = (int*)d_ws;

  detect_kernel<<<dim3(1), dim3(256), 0, stream>>>(ei, (const unsigned short*)x, flags);
  zero_kernel<<<dim3(1200), dim3(256), 0, stream>>>(ws + OFF_DEG, ZERO_COUNT);
  degree_kernel<<<dim3((NE + 255) / 256), dim3(256), 0, stream>>>(ei, ew, ws + OFF_DEG, flags);
  dinv_kernel<<<dim3((NN + 255) / 256), dim3(256), 0, stream>>>(ws + OFF_DEG, ws + OFF_DINV);
  norm_kernel<<<dim3((NE + 255) / 256), dim3(256), 0, stream>>>(ei, ew, ws + OFF_DINV, ws + OFF_NORM, flags);
  gemm1_kernel<<<dim3((NN + 127) / 128), dim3(256), 0, stream>>>(x, W1, ws + OFF_H1, flags);
  scatter1_kernel<<<dim3((NE + 255) / 256), dim3(256), 0, stream>>>(ei, ws + OFF_NORM, ws + OFF_H1, ws + OFF_ACC1, flags);
  relu_proj2_kernel<<<dim3((NN + 15) / 16), dim3(256), 0, stream>>>(ws + OFF_ACC1, ws + OFF_H1, ws + OFF_DINV, b1, W2, ws + OFF_P2, flags);
  scatter2_kernel<<<dim3((NE + 255) / 256), dim3(256), 0, stream>>>(ei, ws + OFF_NORM, ws + OFF_P2, ws + OFF_ACC2, flags);
  finalize_kernel<<<dim3((NN * OUTD + 255) / 256), dim3(256), 0, stream>>>(ws + OFF_ACC2, ws + OFF_P2, ws + OFF_DINV, b2, d_out, flags);
}

// Round 4
// 589.497 us; speedup vs baseline: 7.2319x; 7.2319x over previous
//
#include <hip/hip_runtime.h>
#include <hip/hip_bf16.h>

#define NN   100000
#define NE   1600000
#define FIN  256
#define HID  32
#define OUTD 16
#define NBLK ((NN + 255) / 256)   // 391 scan blocks

// ---- workspace layout (32-bit word offsets) ----
#define OFF_FLAG    0                      // [0]=is64, [1]=isf32
#define OFF_DEG     64                     // NN floats
#define OFF_DINV    (OFF_DEG + NN)         // NN floats
#define OFF_CNT     (OFF_DINV + NN)        // NN ints
#define OFF_CURS    (OFF_CNT + NN)         // NN ints
#define OFF_BSUM    (OFF_CURS + NN)        // 512 ints
#define OFF_BOFF    (OFF_BSUM + 512)       // 512 ints
#define OFF_ROWPTR  (OFF_BOFF + 512)       // NN+1 ints
#define OFF_CSR     (OFF_ROWPTR + NN + 32) // 2*NE words (int2 pairs), 8B aligned
#define OFF_H1      (OFF_CSR + 2*NE)       // NN*HID floats
#define OFF_P2      (OFF_H1 + NN*HID)      // NN*OUTD floats
// total ~8.5M words = 34 MB

__device__ __forceinline__ float bf2f(unsigned short u) {
  union { unsigned int i; float f; } v; v.i = ((unsigned int)u) << 16; return v.f;
}
__device__ __forceinline__ unsigned short f2bf(float f) {
  union { float f; unsigned int i; } v; v.f = f;
  unsigned int x = v.i;
  return (unsigned short)((x + 0x7fffu + ((x >> 16) & 1u)) >> 16); // RNE
}
__device__ __forceinline__ int eidx(const int* __restrict__ ei, long long pos, int is64) {
  return is64 ? ei[2 * pos] : ei[pos];
}
__device__ __forceinline__ float ldf(const void* p, long long i, int isf32) {
  return isf32 ? ((const float*)p)[i] : bf2f(((const unsigned short*)p)[i]);
}

// ---- zero fill ----
__global__ __launch_bounds__(256) void zero_kernel(float* __restrict__ p, int n) {
  int stride = gridDim.x * blockDim.x;
  for (int i = blockIdx.x * blockDim.x + threadIdx.x; i < n; i += stride) p[i] = 0.f;
}

// ---- detect (a) int64 vs int32 edge_index, (b) f32 vs bf16 floats ----
__global__ __launch_bounds__(256) void detect_kernel(const int* __restrict__ ei,
    const unsigned short* __restrict__ xu, int* __restrict__ flags) {
  __shared__ int any, cnt;
  if (threadIdx.x == 0) { any = 0; cnt = 0; }
  __syncthreads();
  int local = 0, c = 0;
  for (int i = threadIdx.x; i < 2048; i += 256) local |= ei[2 * i + 1];
  for (int i = threadIdx.x; i < 1024; i += 256) {
    unsigned int e = (xu[2 * i] >> 7) & 0xFF;
    c += (e < 100 || e > 140) ? 1 : 0;
  }
  if (local) atomicOr(&any, 1);
  atomicAdd(&cnt, c);
  __syncthreads();
  if (threadIdx.x == 0) {
    flags[0] = (any == 0) ? 1 : 0;   // 1 => int64 layout
    flags[1] = (cnt > 100) ? 1 : 0;  // 1 => f32 floats
  }
}

// ---- degree (weighted, float) + in-degree count (int), one pass ----
__global__ __launch_bounds__(256) void degcount_kernel(const int* __restrict__ ei,
    const void* __restrict__ ew, float* __restrict__ deg, int* __restrict__ cnt,
    const int* __restrict__ flags) {
  int e = blockIdx.x * 256 + threadIdx.x;
  if (e >= NE) return;
  int c = eidx(ei, (long long)NE + e, flags[0]);
  atomicAdd(deg + c, ldf(ew, e, flags[1]));
  atomicAdd(cnt + c, 1);
}

// ---- dinv ----
__global__ __launch_bounds__(256) void dinv_kernel(const float* __restrict__ deg,
                                                   float* __restrict__ dinv) {
  int i = blockIdx.x * 256 + threadIdx.x;
  if (i >= NN) return;
  float d = deg[i] + 1.0f;  // self-loop weight 1
  dinv[i] = (d > 0.f) ? rsqrtf(d) : 0.f;
}

// ---- scan k1: per-block sums of cnt ----
__global__ __launch_bounds__(256) void scan_sum_kernel(const int* __restrict__ cnt,
                                                       int* __restrict__ bsum) {
  __shared__ int s[256];
  int i = blockIdx.x * 256 + threadIdx.x;
  s[threadIdx.x] = (i < NN) ? cnt[i] : 0;
  __syncthreads();
  for (int off = 128; off > 0; off >>= 1) {
    if (threadIdx.x < off) s[threadIdx.x] += s[threadIdx.x + off];
    __syncthreads();
  }
  if (threadIdx.x == 0) bsum[blockIdx.x] = s[0];
}

// ---- scan k2: exclusive scan of block sums (single block, 512 thr) ----
__global__ __launch_bounds__(512) void scan_offs_kernel(const int* __restrict__ bsum,
                                                        int* __restrict__ boff) {
  __shared__ int a[512];
  int t = threadIdx.x;
  int orig = (t < NBLK) ? bsum[t] : 0;
  a[t] = orig;
  __syncthreads();
  for (int off = 1; off < 512; off <<= 1) {
    int v = a[t] + ((t >= off) ? a[t - off] : 0);
    __syncthreads();
    a[t] = v;
    __syncthreads();
  }
  if (t < NBLK) boff[t] = a[t] - orig;   // exclusive
}

// ---- scan k3: write rowptr ----
__global__ __launch_bounds__(256) void scan_write_kernel(const int* __restrict__ cnt,
    const int* __restrict__ boff, int* __restrict__ rowptr) {
  __shared__ int a[256];
  int t = threadIdx.x;
  int i = blockIdx.x * 256 + t;
  int orig = (i < NN) ? cnt[i] : 0;
  a[t] = orig;
  __syncthreads();
  for (int off = 1; off < 256; off <<= 1) {
    int v = a[t] + ((t >= off) ? a[t - off] : 0);
    __syncthreads();
    a[t] = v;
    __syncthreads();
  }
  if (i < NN) rowptr[i] = boff[blockIdx.x] + a[t] - orig;  // exclusive
  if (blockIdx.x == 0 && t == 0) rowptr[NN] = NE;
}

// ---- fill CSR: (src, norm) pairs bucketed by dst ----
__global__ __launch_bounds__(256) void fill_csr_kernel(const int* __restrict__ ei,
    const void* __restrict__ ew, const float* __restrict__ dinv,
    const int* __restrict__ rowptr, int* __restrict__ cursor,
    int2* __restrict__ csr, const int* __restrict__ flags) {
  int e = blockIdx.x * 256 + threadIdx.x;
  if (e >= NE) return;
  int is64 = flags[0];
  int r = eidx(ei, e, is64);
  int c = eidx(ei, (long long)NE + e, is64);
  float nw = dinv[r] * ldf(ew, e, flags[1]) * dinv[c];
  int pos = rowptr[c] + atomicAdd(cursor + c, 1);
  int2 pr; pr.x = r; pr.y = __float_as_int(nw);
  csr[pos] = pr;
}

// ---- gemm1: h1 = x @ W1   [NN,256]x[256,32] ----
__global__ __launch_bounds__(256) void gemm1_kernel(const void* __restrict__ x,
    const void* __restrict__ W1, float* __restrict__ h1,
    const int* __restrict__ flags) {
  __shared__ float wlds[FIN][HID];   // 32 KB
  __shared__ float xs[32][132];      // transposed [k][row], padded
  int t = threadIdx.x;
  int rb = blockIdx.x * 128;
  int isf32 = flags[1];

  if (isf32) {
    const float* wrow = (const float*)W1 + t * HID;
    #pragma unroll
    for (int jj = 0; jj < HID; jj += 4)
      *(float4*)&wlds[t][jj] = *((const float4*)(wrow + jj));
  } else {
    const unsigned short* wrow = (const unsigned short*)W1 + t * HID;
    #pragma unroll
    for (int jj = 0; jj < HID; jj += 8) {
      uint4 pk = *((const uint4*)(wrow + jj));
      const unsigned short* pu = (const unsigned short*)&pk;
      #pragma unroll
      for (int q = 0; q < 8; q++) wlds[t][jj + q] = bf2f(pu[q]);
    }
  }

  int j0 = (t & 15) * 2;
  int r0 = (t >> 4) * 8;
  float acc[8][2];
  #pragma unroll
  for (int i = 0; i < 8; i++) { acc[i][0] = 0.f; acc[i][1] = 0.f; }

  for (int kc = 0; kc < FIN; kc += 32) {
    __syncthreads();
    {
      int rr = t >> 1;
      int kk0 = (t & 1) * 16;
      int grow = rb + rr;
      if (grow < NN) {
        if (isf32) {
          const float* xp = (const float*)x + (long long)grow * FIN + kc + kk0;
          #pragma unroll
          for (int q4 = 0; q4 < 4; q4++) {
            float4 p = ((const float4*)xp)[q4];
            xs[kk0 + q4 * 4 + 0][rr] = p.x;
            xs[kk0 + q4 * 4 + 1][rr] = p.y;
            xs[kk0 + q4 * 4 + 2][rr] = p.z;
            xs[kk0 + q4 * 4 + 3][rr] = p.w;
          }
        } else {
          const unsigned short* xp = (const unsigned short*)x + (long long)grow * FIN + kc + kk0;
          uint4 p0 = ((const uint4*)xp)[0];
          uint4 p1 = ((const uint4*)xp)[1];
          const unsigned short* pu = (const unsigned short*)&p0;
          #pragma unroll
          for (int q = 0; q < 8; q++) xs[kk0 + q][rr] = bf2f(pu[q]);
          pu = (const unsigned short*)&p1;
          #pragma unroll
          for (int q = 0; q < 8; q++) xs[kk0 + 8 + q][rr] = bf2f(pu[q]);
        }
      } else {
        #pragma unroll
        for (int q = 0; q < 16; q++) xs[kk0 + q][rr] = 0.f;
      }
    }
    __syncthreads();
    #pragma unroll 8
    for (int kk = 0; kk < 32; kk++) {
      float w0 = wlds[kc + kk][j0];
      float w1 = wlds[kc + kk][j0 + 1];
      const float4* xr = (const float4*)&xs[kk][r0];
      float4 xa = xr[0], xb = xr[1];
      float xv[8] = {xa.x, xa.y, xa.z, xa.w, xb.x, xb.y, xb.z, xb.w};
      #pragma unroll
      for (int i = 0; i < 8; i++) {
        acc[i][0] = fmaf(xv[i], w0, acc[i][0]);
        acc[i][1] = fmaf(xv[i], w1, acc[i][1]);
      }
    }
  }
  #pragma unroll
  for (int i = 0; i < 8; i++) {
    int grow = rb + r0 + i;
    if (grow < NN) {
      float2 v; v.x = acc[i][0]; v.y = acc[i][1];
      *((float2*)(h1 + (long long)grow * HID + j0)) = v;
    }
  }
}

// ---- gather1 fused: conv1 aggregate + self-loop + bias + ReLU + @W2 -> p2 ----
// 256 threads = 8 nodes x 32 lanes (lane = feature j)
__global__ __launch_bounds__(256) void gather1_kernel(const float* __restrict__ h1,
    const float* __restrict__ dinv, const int* __restrict__ rowptr,
    const int2* __restrict__ csr, const void* __restrict__ b1,
    const void* __restrict__ W2, float* __restrict__ p2,
    const int* __restrict__ flags) {
  __shared__ float w2lds[HID * OUTD];  // [k][m] flat
  __shared__ float b1l[HID];
  __shared__ float tl[8][HID + 1];
  int t = threadIdx.x;
  int isf32 = flags[1];
  w2lds[2 * t]     = ldf(W2, 2 * t, isf32);
  w2lds[2 * t + 1] = ldf(W2, 2 * t + 1, isf32);
  if (t < HID) b1l[t] = ldf(b1, t, isf32);
  __syncthreads();  // b1l/w2lds read by all threads below

  int nl = t >> 5;          // node slot 0..7
  int j  = t & 31;          // feature
  int node = blockIdx.x * 8 + nl;
  if (node < NN) {
    int k0 = rowptr[node], k1 = rowptr[node + 1];
    float acc = 0.f;
    for (int k = k0; k < k1; k++) {
      int2 pr = csr[k];                       // 8B broadcast within lane-group
      acc = fmaf(__int_as_float(pr.y), h1[(long long)pr.x * HID + j], acc);
    }
    float di = dinv[node];
    acc = fmaf(di * di, h1[(long long)node * HID + j], acc);
    acc += b1l[j];
    tl[nl][j] = fmaxf(acc, 0.f);
  }
  __syncthreads();
  int m = t & 31;
  if (node < NN && m < OUTD) {
    float s = 0.f;
    #pragma unroll
    for (int k = 0; k < HID; k++) s = fmaf(tl[nl][k], w2lds[k * OUTD + m], s);
    p2[(long long)node * OUTD + m] = s;
  }
}

// ---- gather2: conv2 aggregate + self-loop + bias -> out ----
// 256 threads = 16 nodes x 16 lanes (lane = feature m)
__global__ __launch_bounds__(256) void gather2_kernel(const float* __restrict__ p2,
    const float* __restrict__ dinv, const int* __restrict__ rowptr,
    const int2* __restrict__ csr, const void* __restrict__ b2,
    void* __restrict__ out, const int* __restrict__ flags) {
  __shared__ float b2l[OUTD];
  int t = threadIdx.x;
  int isf32 = flags[1];
  if (t < OUTD) b2l[t] = ldf(b2, t, isf32);
  __syncthreads();

  int nl = t >> 4;
  int m  = t & 15;
  int node = blockIdx.x * 16 + nl;
  if (node >= NN) return;
  int k0 = rowptr[node], k1 = rowptr[node + 1];
  float acc = 0.f;
  for (int k = k0; k < k1; k++) {
    int2 pr = csr[k];
    acc = fmaf(__int_as_float(pr.y), p2[(long long)pr.x * OUTD + m], acc);
  }
  float di = dinv[node];
  acc = fmaf(di * di, p2[(long long)node * OUTD + m], acc);
  acc += b2l[m];
  long long oidx = (long long)node * OUTD + m;
  if (isf32) ((float*)out)[oidx] = acc;
  else       ((unsigned short*)out)[oidx] = f2bf(acc);
}

extern "C" void kernel_launch(void* const* d_in, const int* in_sizes, int n_in,
                              void* d_out, int out_size, void* d_ws, size_t ws_size,
                              hipStream_t stream) {
  const void* x  = d_in[0];
  const int* ei  = (const int*)d_in[1];
  const void* ew = d_in[2];
  const void* W1 = d_in[3];
  const void* b1 = d_in[4];
  const void* W2 = d_in[5];
  const void* b2 = d_in[6];
  float* ws = (float*)d_ws;
  int* wsi = (int*)d_ws;

  detect_kernel<<<dim3(1), dim3(256), 0, stream>>>(ei, (const unsigned short*)x, wsi + OFF_FLAG);
  // zero deg, dinv, cnt, cursor (contiguous 3*NN words starting at OFF_DEG... includes dinv, harmless)
  zero_kernel<<<dim3(512), dim3(256), 0, stream>>>(ws + OFF_DEG, 4 * NN);
  degcount_kernel<<<dim3((NE + 255) / 256), dim3(256), 0, stream>>>(ei, ew, ws + OFF_DEG, wsi + OFF_CNT, wsi + OFF_FLAG);
  dinv_kernel<<<dim3(NBLK), dim3(256), 0, stream>>>(ws + OFF_DEG, ws + OFF_DINV);
  scan_sum_kernel<<<dim3(NBLK), dim3(256), 0, stream>>>(wsi + OFF_CNT, wsi + OFF_BSUM);
  scan_offs_kernel<<<dim3(1), dim3(512), 0, stream>>>(wsi + OFF_BSUM, wsi + OFF_BOFF);
  scan_write_kernel<<<dim3(NBLK), dim3(256), 0, stream>>>(wsi + OFF_CNT, wsi + OFF_BOFF, wsi + OFF_ROWPTR);
  fill_csr_kernel<<<dim3((NE + 255) / 256), dim3(256), 0, stream>>>(ei, ew, ws + OFF_DINV, wsi + OFF_ROWPTR, wsi + OFF_CURS, (int2*)(wsi + OFF_CSR), wsi + OFF_FLAG);
  gemm1_kernel<<<dim3((NN + 127) / 128), dim3(256), 0, stream>>>(x, W1, ws + OFF_H1, wsi + OFF_FLAG);
  gather1_kernel<<<dim3((NN + 7) / 8), dim3(256), 0, stream>>>(ws + OFF_H1, ws + OFF_DINV, wsi + OFF_ROWPTR, (const int2*)(wsi + OFF_CSR), b1, W2, ws + OFF_P2, wsi + OFF_FLAG);
  gather2_kernel<<<dim3((NN + 15) / 16), dim3(256), 0, stream>>>(ws + OFF_P2, ws + OFF_DINV, wsi + OFF_ROWPTR, (const int2*)(wsi + OFF_CSR), b2, d_out, wsi + OFF_FLAG);
}

// Round 5
// 483.182 us; speedup vs baseline: 8.8231x; 1.2200x over previous
//
#include <hip/hip_runtime.h>
#include <hip/hip_bf16.h>

#define NN   100000
#define NE   1600000
#define FIN  256
#define HID  32
#define OUTD 16
#define NBLK ((NN + 255) / 256)   // 391 scan blocks

// ---- workspace layout (32-bit word offsets), total ~10.0M words = 40 MB ----
#define OFF_FLAG    0                      // [0]=is64, [1]=isf32
#define OFF_DEGPACK 64                     // NN u64 (2*NN words), 8B-aligned
#define OFF_DINV    (OFF_DEGPACK + 2*NN)   // NN floats
#define OFF_RANK    (OFF_DINV + NN)        // NE ints
#define OFF_BSUM    (OFF_RANK + NE)        // 512 ints
#define OFF_BOFF    (OFF_BSUM + 512)       // 512 ints
#define OFF_ROWPTR  (OFF_BOFF + 512)       // NN+1 ints
#define OFF_CSR     (OFF_ROWPTR + NN + 32) // 2*NE words (int2 pairs), 8B-aligned
#define OFF_H1      (OFF_CSR + 2*NE)       // NN*HID floats
#define OFF_P2      (OFF_H1 + NN*HID)      // NN*OUTD floats

#define PACK_SHIFT 40
#define PACK_MASK  ((1ull << PACK_SHIFT) - 1ull)
#define FP_SCALE   16777216.0f             // 2^24
#define FP_INV     (1.0f / 16777216.0f)

__device__ __forceinline__ float bf2f(unsigned short u) {
  union { unsigned int i; float f; } v; v.i = ((unsigned int)u) << 16; return v.f;
}
__device__ __forceinline__ unsigned short f2bf(float f) {
  union { float f; unsigned int i; } v; v.f = f;
  unsigned int x = v.i;
  return (unsigned short)((x + 0x7fffu + ((x >> 16) & 1u)) >> 16); // RNE
}
__device__ __forceinline__ int eidx(const int* __restrict__ ei, long long pos, int is64) {
  return is64 ? ei[2 * pos] : ei[pos];
}
__device__ __forceinline__ float ldf(const void* p, long long i, int isf32) {
  return isf32 ? ((const float*)p)[i] : bf2f(((const unsigned short*)p)[i]);
}

// ---- zero fill ----
__global__ __launch_bounds__(256) void zero_kernel(float* __restrict__ p, int n) {
  int stride = gridDim.x * blockDim.x;
  for (int i = blockIdx.x * blockDim.x + threadIdx.x; i < n; i += stride) p[i] = 0.f;
}

// ---- detect (a) int64 vs int32 edge_index, (b) f32 vs bf16 floats ----
__global__ __launch_bounds__(256) void detect_kernel(const int* __restrict__ ei,
    const unsigned short* __restrict__ xu, int* __restrict__ flags) {
  __shared__ int any, cnt;
  if (threadIdx.x == 0) { any = 0; cnt = 0; }
  __syncthreads();
  int local = 0, c = 0;
  for (int i = threadIdx.x; i < 2048; i += 256) local |= ei[2 * i + 1];
  for (int i = threadIdx.x; i < 1024; i += 256) {
    unsigned int e = (xu[2 * i] >> 7) & 0xFF;
    c += (e < 100 || e > 140) ? 1 : 0;
  }
  if (local) atomicOr(&any, 1);
  atomicAdd(&cnt, c);
  __syncthreads();
  if (threadIdx.x == 0) {
    flags[0] = (any == 0) ? 1 : 0;   // 1 => int64 layout
    flags[1] = (cnt > 100) ? 1 : 0;  // 1 => f32 floats
  }
}

// ---- ONE atomic pass: packed (count<<40 | fixedpoint weight) + rank harvest ----
__global__ __launch_bounds__(256) void count_rank_kernel(const int* __restrict__ ei,
    const void* __restrict__ ew, unsigned long long* __restrict__ degpack,
    int* __restrict__ rank, const int* __restrict__ flags) {
  int e = blockIdx.x * 256 + threadIdx.x;
  if (e >= NE) return;
  int c = eidx(ei, (long long)NE + e, flags[0]);
  float w = ldf(ew, e, flags[1]);
  unsigned long long inc = (1ull << PACK_SHIFT)
                         | (unsigned long long)(w * FP_SCALE + 0.5f);
  unsigned long long old = atomicAdd(degpack + c, inc);
  rank[e] = (int)(old >> PACK_SHIFT);     // within-bucket position
}

// ---- dinv from packed weighted degree ----
__global__ __launch_bounds__(256) void dinv_kernel(const unsigned long long* __restrict__ degpack,
                                                   float* __restrict__ dinv) {
  int i = blockIdx.x * 256 + threadIdx.x;
  if (i >= NN) return;
  float d = (float)(degpack[i] & PACK_MASK) * FP_INV + 1.0f;  // + self-loop
  dinv[i] = (d > 0.f) ? rsqrtf(d) : 0.f;
}

// ---- scan k1: per-block sums of counts ----
__global__ __launch_bounds__(256) void scan_sum_kernel(const unsigned long long* __restrict__ degpack,
                                                       int* __restrict__ bsum) {
  __shared__ int s[256];
  int i = blockIdx.x * 256 + threadIdx.x;
  s[threadIdx.x] = (i < NN) ? (int)(degpack[i] >> PACK_SHIFT) : 0;
  __syncthreads();
  for (int off = 128; off > 0; off >>= 1) {
    if (threadIdx.x < off) s[threadIdx.x] += s[threadIdx.x + off];
    __syncthreads();
  }
  if (threadIdx.x == 0) bsum[blockIdx.x] = s[0];
}

// ---- scan k2: exclusive scan of block sums (single block, 512 thr) ----
__global__ __launch_bounds__(512) void scan_offs_kernel(const int* __restrict__ bsum,
                                                        int* __restrict__ boff) {
  __shared__ int a[512];
  int t = threadIdx.x;
  int orig = (t < NBLK) ? bsum[t] : 0;
  a[t] = orig;
  __syncthreads();
  for (int off = 1; off < 512; off <<= 1) {
    int v = a[t] + ((t >= off) ? a[t - off] : 0);
    __syncthreads();
    a[t] = v;
    __syncthreads();
  }
  if (t < NBLK) boff[t] = a[t] - orig;   // exclusive
}

// ---- scan k3: write rowptr ----
__global__ __launch_bounds__(256) void scan_write_kernel(const unsigned long long* __restrict__ degpack,
    const int* __restrict__ boff, int* __restrict__ rowptr) {
  __shared__ int a[256];
  int t = threadIdx.x;
  int i = blockIdx.x * 256 + t;
  int orig = (i < NN) ? (int)(degpack[i] >> PACK_SHIFT) : 0;
  a[t] = orig;
  __syncthreads();
  for (int off = 1; off < 256; off <<= 1) {
    int v = a[t] + ((t >= off) ? a[t - off] : 0);
    __syncthreads();
    a[t] = v;
    __syncthreads();
  }
  if (i < NN) rowptr[i] = boff[blockIdx.x] + a[t] - orig;  // exclusive
  if (blockIdx.x == 0 && t == 0) rowptr[NN] = NE;
}

// ---- fill CSR: (src, norm) pairs bucketed by dst — NO atomics ----
__global__ __launch_bounds__(256) void fill_csr_kernel(const int* __restrict__ ei,
    const void* __restrict__ ew, const float* __restrict__ dinv,
    const int* __restrict__ rowptr, const int* __restrict__ rank,
    int2* __restrict__ csr, const int* __restrict__ flags) {
  int e = blockIdx.x * 256 + threadIdx.x;
  if (e >= NE) return;
  int is64 = flags[0];
  int r = eidx(ei, e, is64);
  int c = eidx(ei, (long long)NE + e, is64);
  float nw = dinv[r] * ldf(ew, e, flags[1]) * dinv[c];
  int pos = rowptr[c] + rank[e];
  int2 pr; pr.x = r; pr.y = __float_as_int(nw);
  csr[pos] = pr;
}

// ---- gemm1: h1 = x @ W1   [NN,256]x[256,32] ----
__global__ __launch_bounds__(256) void gemm1_kernel(const void* __restrict__ x,
    const void* __restrict__ W1, float* __restrict__ h1,
    const int* __restrict__ flags) {
  __shared__ float wlds[FIN][HID];   // 32 KB
  __shared__ float xs[32][132];      // transposed [k][row], padded
  int t = threadIdx.x;
  int rb = blockIdx.x * 128;
  int isf32 = flags[1];

  if (isf32) {
    const float* wrow = (const float*)W1 + t * HID;
    #pragma unroll
    for (int jj = 0; jj < HID; jj += 4)
      *(float4*)&wlds[t][jj] = *((const float4*)(wrow + jj));
  } else {
    const unsigned short* wrow = (const unsigned short*)W1 + t * HID;
    #pragma unroll
    for (int jj = 0; jj < HID; jj += 8) {
      uint4 pk = *((const uint4*)(wrow + jj));
      const unsigned short* pu = (const unsigned short*)&pk;
      #pragma unroll
      for (int q = 0; q < 8; q++) wlds[t][jj + q] = bf2f(pu[q]);
    }
  }

  int j0 = (t & 15) * 2;
  int r0 = (t >> 4) * 8;
  float acc[8][2];
  #pragma unroll
  for (int i = 0; i < 8; i++) { acc[i][0] = 0.f; acc[i][1] = 0.f; }

  for (int kc = 0; kc < FIN; kc += 32) {
    __syncthreads();
    {
      int rr = t >> 1;
      int kk0 = (t & 1) * 16;
      int grow = rb + rr;
      if (grow < NN) {
        if (isf32) {
          const float* xp = (const float*)x + (long long)grow * FIN + kc + kk0;
          #pragma unroll
          for (int q4 = 0; q4 < 4; q4++) {
            float4 p = ((const float4*)xp)[q4];
            xs[kk0 + q4 * 4 + 0][rr] = p.x;
            xs[kk0 + q4 * 4 + 1][rr] = p.y;
            xs[kk0 + q4 * 4 + 2][rr] = p.z;
            xs[kk0 + q4 * 4 + 3][rr] = p.w;
          }
        } else {
          const unsigned short* xp = (const unsigned short*)x + (long long)grow * FIN + kc + kk0;
          uint4 p0 = ((const uint4*)xp)[0];
          uint4 p1 = ((const uint4*)xp)[1];
          const unsigned short* pu = (const unsigned short*)&p0;
          #pragma unroll
          for (int q = 0; q < 8; q++) xs[kk0 + q][rr] = bf2f(pu[q]);
          pu = (const unsigned short*)&p1;
          #pragma unroll
          for (int q = 0; q < 8; q++) xs[kk0 + 8 + q][rr] = bf2f(pu[q]);
        }
      } else {
        #pragma unroll
        for (int q = 0; q < 16; q++) xs[kk0 + q][rr] = 0.f;
      }
    }
    __syncthreads();
    #pragma unroll 8
    for (int kk = 0; kk < 32; kk++) {
      float w0 = wlds[kc + kk][j0];
      float w1 = wlds[kc + kk][j0 + 1];
      const float4* xr = (const float4*)&xs[kk][r0];
      float4 xa = xr[0], xb = xr[1];
      float xv[8] = {xa.x, xa.y, xa.z, xa.w, xb.x, xb.y, xb.z, xb.w};
      #pragma unroll
      for (int i = 0; i < 8; i++) {
        acc[i][0] = fmaf(xv[i], w0, acc[i][0]);
        acc[i][1] = fmaf(xv[i], w1, acc[i][1]);
      }
    }
  }
  #pragma unroll
  for (int i = 0; i < 8; i++) {
    int grow = rb + r0 + i;
    if (grow < NN) {
      float2 v; v.x = acc[i][0]; v.y = acc[i][1];
      *((float2*)(h1 + (long long)grow * HID + j0)) = v;
    }
  }
}

// ---- gather1 fused: conv1 aggregate + self-loop + bias + ReLU + @W2 -> p2 ----
// 256 threads = 8 nodes x 32 lanes (lane = feature j)
__global__ __launch_bounds__(256) void gather1_kernel(const float* __restrict__ h1,
    const float* __restrict__ dinv, const int* __restrict__ rowptr,
    const int2* __restrict__ csr, const void* __restrict__ b1,
    const void* __restrict__ W2, float* __restrict__ p2,
    const int* __restrict__ flags) {
  __shared__ float w2lds[HID * OUTD];  // [k][m] flat
  __shared__ float b1l[HID];
  __shared__ float tl[8][HID + 1];
  int t = threadIdx.x;
  int isf32 = flags[1];
  w2lds[2 * t]     = ldf(W2, 2 * t, isf32);
  w2lds[2 * t + 1] = ldf(W2, 2 * t + 1, isf32);
  if (t < HID) b1l[t] = ldf(b1, t, isf32);
  __syncthreads();  // b1l/w2lds read by all threads below

  int nl = t >> 5;          // node slot 0..7
  int j  = t & 31;          // feature
  int node = blockIdx.x * 8 + nl;
  if (node < NN) {
    int k0 = rowptr[node], k1 = rowptr[node + 1];
    float acc = 0.f;
    for (int k = k0; k < k1; k++) {
      int2 pr = csr[k];                       // 8B broadcast within lane-group
      acc = fmaf(__int_as_float(pr.y), h1[(long long)pr.x * HID + j], acc);
    }
    float di = dinv[node];
    acc = fmaf(di * di, h1[(long long)node * HID + j], acc);
    acc += b1l[j];
    tl[nl][j] = fmaxf(acc, 0.f);
  }
  __syncthreads();
  int m = t & 31;
  if (node < NN && m < OUTD) {
    float s = 0.f;
    #pragma unroll
    for (int k = 0; k < HID; k++) s = fmaf(tl[nl][k], w2lds[k * OUTD + m], s);
    p2[(long long)node * OUTD + m] = s;
  }
}

// ---- gather2: conv2 aggregate + self-loop + bias -> out ----
// 256 threads = 16 nodes x 16 lanes (lane = feature m)
__global__ __launch_bounds__(256) void gather2_kernel(const float* __restrict__ p2,
    const float* __restrict__ dinv, const int* __restrict__ rowptr,
    const int2* __restrict__ csr, const void* __restrict__ b2,
    void* __restrict__ out, const int* __restrict__ flags) {
  __shared__ float b2l[OUTD];
  int t = threadIdx.x;
  int isf32 = flags[1];
  if (t < OUTD) b2l[t] = ldf(b2, t, isf32);
  __syncthreads();

  int nl = t >> 4;
  int m  = t & 15;
  int node = blockIdx.x * 16 + nl;
  if (node >= NN) return;
  int k0 = rowptr[node], k1 = rowptr[node + 1];
  float acc = 0.f;
  for (int k = k0; k < k1; k++) {
    int2 pr = csr[k];
    acc = fmaf(__int_as_float(pr.y), p2[(long long)pr.x * OUTD + m], acc);
  }
  float di = dinv[node];
  acc = fmaf(di * di, p2[(long long)node * OUTD + m], acc);
  acc += b2l[m];
  long long oidx = (long long)node * OUTD + m;
  if (isf32) ((float*)out)[oidx] = acc;
  else       ((unsigned short*)out)[oidx] = f2bf(acc);
}

extern "C" void kernel_launch(void* const* d_in, const int* in_sizes, int n_in,
                              void* d_out, int out_size, void* d_ws, size_t ws_size,
                              hipStream_t stream) {
  const void* x  = d_in[0];
  const int* ei  = (const int*)d_in[1];
  const void* ew = d_in[2];
  const void* W1 = d_in[3];
  const void* b1 = d_in[4];
  const void* W2 = d_in[5];
  const void* b2 = d_in[6];
  float* ws = (float*)d_ws;
  int* wsi = (int*)d_ws;
  unsigned long long* degpack = (unsigned long long*)(wsi + OFF_DEGPACK);

  detect_kernel<<<dim3(1), dim3(256), 0, stream>>>(ei, (const unsigned short*)x, wsi + OFF_FLAG);
  zero_kernel<<<dim3(512), dim3(256), 0, stream>>>(ws + OFF_DEGPACK, 2 * NN);  // degpack only
  count_rank_kernel<<<dim3((NE + 255) / 256), dim3(256), 0, stream>>>(ei, ew, degpack, wsi + OFF_RANK, wsi + OFF_FLAG);
  dinv_kernel<<<dim3(NBLK), dim3(256), 0, stream>>>(degpack, ws + OFF_DINV);
  scan_sum_kernel<<<dim3(NBLK), dim3(256), 0, stream>>>(degpack, wsi + OFF_BSUM);
  scan_offs_kernel<<<dim3(1), dim3(512), 0, stream>>>(wsi + OFF_BSUM, wsi + OFF_BOFF);
  scan_write_kernel<<<dim3(NBLK), dim3(256), 0, stream>>>(degpack, wsi + OFF_BOFF, wsi + OFF_ROWPTR);
  fill_csr_kernel<<<dim3((NE + 255) / 256), dim3(256), 0, stream>>>(ei, ew, ws + OFF_DINV, wsi + OFF_ROWPTR, wsi + OFF_RANK, (int2*)(wsi + OFF_CSR), wsi + OFF_FLAG);
  gemm1_kernel<<<dim3((NN + 127) / 128), dim3(256), 0, stream>>>(x, W1, ws + OFF_H1, wsi + OFF_FLAG);
  gather1_kernel<<<dim3((NN + 7) / 8), dim3(256), 0, stream>>>(ws + OFF_H1, ws + OFF_DINV, wsi + OFF_ROWPTR, (const int2*)(wsi + OFF_CSR), b1, W2, ws + OFF_P2, wsi + OFF_FLAG);
  gather2_kernel<<<dim3((NN + 15) / 16), dim3(256), 0, stream>>>(ws + OFF_P2, ws + OFF_DINV, wsi + OFF_ROWPTR, (const int2*)(wsi + OFF_CSR), b2, d_out, wsi + OFF_FLAG);
}

// Round 6
// 413.157 us; speedup vs baseline: 10.3185x; 1.1695x over previous
//
#include <hip/hip_runtime.h>
#include <hip/hip_bf16.h>

#define NN   100000
#define NE   1600000
#define FIN  256
#define HID  32
#define OUTD 16
#define NBLK ((NN + 255) / 256)   // 391 scan blocks

// ---- workspace layout (32-bit word offsets), total ~10.0M words = 40 MB ----
#define OFF_FLAG    0                      // [0]=is64, [1]=isf32
#define OFF_DEGPACK 64                     // NN u64 (2*NN words), 8B-aligned
#define OFF_DINV    (OFF_DEGPACK + 2*NN)   // NN floats
#define OFF_RANK    (OFF_DINV + NN)        // NE ints
#define OFF_BSUM    (OFF_RANK + NE)        // 512 ints
#define OFF_BOFF    (OFF_BSUM + 512)       // 512 ints
#define OFF_ROWPTR  (OFF_BOFF + 512)       // NN+1 ints
#define OFF_CSR     (OFF_ROWPTR + NN + 32) // 2*NE words (int2 pairs), 8B-aligned
#define OFF_H1      (OFF_CSR + 2*NE)       // NN*HID floats
#define OFF_P2      (OFF_H1 + NN*HID)      // NN*OUTD floats

#define PACK_SHIFT 40
#define PACK_MASK  ((1ull << PACK_SHIFT) - 1ull)
#define FP_SCALE   16777216.0f             // 2^24
#define FP_INV     (1.0f / 16777216.0f)

__device__ __forceinline__ float bf2f(unsigned short u) {
  union { unsigned int i; float f; } v; v.i = ((unsigned int)u) << 16; return v.f;
}
__device__ __forceinline__ unsigned short f2bf(float f) {
  union { float f; unsigned int i; } v; v.f = f;
  unsigned int x = v.i;
  return (unsigned short)((x + 0x7fffu + ((x >> 16) & 1u)) >> 16); // RNE
}
__device__ __forceinline__ int eidx(const int* __restrict__ ei, long long pos, int is64) {
  return is64 ? ei[2 * pos] : ei[pos];
}
__device__ __forceinline__ float ldf(const void* p, long long i, int isf32) {
  return isf32 ? ((const float*)p)[i] : bf2f(((const unsigned short*)p)[i]);
}

// ---- zero fill ----
__global__ __launch_bounds__(256) void zero_kernel(float* __restrict__ p, int n) {
  int stride = gridDim.x * blockDim.x;
  for (int i = blockIdx.x * blockDim.x + threadIdx.x; i < n; i += stride) p[i] = 0.f;
}

// ---- detect (a) int64 vs int32 edge_index, (b) f32 vs bf16 floats ----
__global__ __launch_bounds__(256) void detect_kernel(const int* __restrict__ ei,
    const unsigned short* __restrict__ xu, int* __restrict__ flags) {
  __shared__ int any, cnt;
  if (threadIdx.x == 0) { any = 0; cnt = 0; }
  __syncthreads();
  int local = 0, c = 0;
  for (int i = threadIdx.x; i < 2048; i += 256) local |= ei[2 * i + 1];
  for (int i = threadIdx.x; i < 1024; i += 256) {
    unsigned int e = (xu[2 * i] >> 7) & 0xFF;
    c += (e < 100 || e > 140) ? 1 : 0;
  }
  if (local) atomicOr(&any, 1);
  atomicAdd(&cnt, c);
  __syncthreads();
  if (threadIdx.x == 0) {
    flags[0] = (any == 0) ? 1 : 0;   // 1 => int64 layout
    flags[1] = (cnt > 100) ? 1 : 0;  // 1 => f32 floats
  }
}

// ---- ONE atomic pass: packed (count<<40 | fixedpoint weight) + rank harvest ----
__global__ __launch_bounds__(256) void count_rank_kernel(const int* __restrict__ ei,
    const void* __restrict__ ew, unsigned long long* __restrict__ degpack,
    int* __restrict__ rank, const int* __restrict__ flags) {
  int e = blockIdx.x * 256 + threadIdx.x;
  if (e >= NE) return;
  int c = eidx(ei, (long long)NE + e, flags[0]);
  float w = ldf(ew, e, flags[1]);
  unsigned long long inc = (1ull << PACK_SHIFT)
                         | (unsigned long long)(w * FP_SCALE + 0.5f);
  unsigned long long old = atomicAdd(degpack + c, inc);
  rank[e] = (int)(old >> PACK_SHIFT);     // within-bucket position
}

// ---- dinv from packed weighted degree ----
__global__ __launch_bounds__(256) void dinv_kernel(const unsigned long long* __restrict__ degpack,
                                                   float* __restrict__ dinv) {
  int i = blockIdx.x * 256 + threadIdx.x;
  if (i >= NN) return;
  float d = (float)(degpack[i] & PACK_MASK) * FP_INV + 1.0f;  // + self-loop
  dinv[i] = (d > 0.f) ? rsqrtf(d) : 0.f;
}

// ---- scan k1: per-block sums of counts ----
__global__ __launch_bounds__(256) void scan_sum_kernel(const unsigned long long* __restrict__ degpack,
                                                       int* __restrict__ bsum) {
  __shared__ int s[256];
  int i = blockIdx.x * 256 + threadIdx.x;
  s[threadIdx.x] = (i < NN) ? (int)(degpack[i] >> PACK_SHIFT) : 0;
  __syncthreads();
  for (int off = 128; off > 0; off >>= 1) {
    if (threadIdx.x < off) s[threadIdx.x] += s[threadIdx.x + off];
    __syncthreads();
  }
  if (threadIdx.x == 0) bsum[blockIdx.x] = s[0];
}

// ---- scan k2: exclusive scan of block sums (single block, 512 thr) ----
__global__ __launch_bounds__(512) void scan_offs_kernel(const int* __restrict__ bsum,
                                                        int* __restrict__ boff) {
  __shared__ int a[512];
  int t = threadIdx.x;
  int orig = (t < NBLK) ? bsum[t] : 0;
  a[t] = orig;
  __syncthreads();
  for (int off = 1; off < 512; off <<= 1) {
    int v = a[t] + ((t >= off) ? a[t - off] : 0);
    __syncthreads();
    a[t] = v;
    __syncthreads();
  }
  if (t < NBLK) boff[t] = a[t] - orig;   // exclusive
}

// ---- scan k3: write rowptr ----
__global__ __launch_bounds__(256) void scan_write_kernel(const unsigned long long* __restrict__ degpack,
    const int* __restrict__ boff, int* __restrict__ rowptr) {
  __shared__ int a[256];
  int t = threadIdx.x;
  int i = blockIdx.x * 256 + t;
  int orig = (i < NN) ? (int)(degpack[i] >> PACK_SHIFT) : 0;
  a[t] = orig;
  __syncthreads();
  for (int off = 1; off < 256; off <<= 1) {
    int v = a[t] + ((t >= off) ? a[t - off] : 0);
    __syncthreads();
    a[t] = v;
    __syncthreads();
  }
  if (i < NN) rowptr[i] = boff[blockIdx.x] + a[t] - orig;  // exclusive
  if (blockIdx.x == 0 && t == 0) rowptr[NN] = NE;
}

// ---- fill CSR: (src, norm) pairs bucketed by dst — NO atomics ----
__global__ __launch_bounds__(256) void fill_csr_kernel(const int* __restrict__ ei,
    const void* __restrict__ ew, const float* __restrict__ dinv,
    const int* __restrict__ rowptr, const int* __restrict__ rank,
    int2* __restrict__ csr, const int* __restrict__ flags) {
  int e = blockIdx.x * 256 + threadIdx.x;
  if (e >= NE) return;
  int is64 = flags[0];
  int r = eidx(ei, e, is64);
  int c = eidx(ei, (long long)NE + e, is64);
  float nw = dinv[r] * ldf(ew, e, flags[1]) * dinv[c];
  int pos = rowptr[c] + rank[e];
  int2 pr; pr.x = r; pr.y = __float_as_int(nw);
  csr[pos] = pr;
}

// ---- gemm1: h1 = x @ W1   [NN,256]x[256,32] ----
__global__ __launch_bounds__(256) void gemm1_kernel(const void* __restrict__ x,
    const void* __restrict__ W1, float* __restrict__ h1,
    const int* __restrict__ flags) {
  __shared__ float wlds[FIN][HID];   // 32 KB
  __shared__ float xs[32][132];      // transposed [k][row], padded
  int t = threadIdx.x;
  int rb = blockIdx.x * 128;
  int isf32 = flags[1];

  if (isf32) {
    const float* wrow = (const float*)W1 + t * HID;
    #pragma unroll
    for (int jj = 0; jj < HID; jj += 4)
      *(float4*)&wlds[t][jj] = *((const float4*)(wrow + jj));
  } else {
    const unsigned short* wrow = (const unsigned short*)W1 + t * HID;
    #pragma unroll
    for (int jj = 0; jj < HID; jj += 8) {
      uint4 pk = *((const uint4*)(wrow + jj));
      const unsigned short* pu = (const unsigned short*)&pk;
      #pragma unroll
      for (int q = 0; q < 8; q++) wlds[t][jj + q] = bf2f(pu[q]);
    }
  }

  int j0 = (t & 15) * 2;
  int r0 = (t >> 4) * 8;
  float acc[8][2];
  #pragma unroll
  for (int i = 0; i < 8; i++) { acc[i][0] = 0.f; acc[i][1] = 0.f; }

  for (int kc = 0; kc < FIN; kc += 32) {
    __syncthreads();
    {
      int rr = t >> 1;
      int kk0 = (t & 1) * 16;
      int grow = rb + rr;
      if (grow < NN) {
        if (isf32) {
          const float* xp = (const float*)x + (long long)grow * FIN + kc + kk0;
          #pragma unroll
          for (int q4 = 0; q4 < 4; q4++) {
            float4 p = ((const float4*)xp)[q4];
            xs[kk0 + q4 * 4 + 0][rr] = p.x;
            xs[kk0 + q4 * 4 + 1][rr] = p.y;
            xs[kk0 + q4 * 4 + 2][rr] = p.z;
            xs[kk0 + q4 * 4 + 3][rr] = p.w;
          }
        } else {
          const unsigned short* xp = (const unsigned short*)x + (long long)grow * FIN + kc + kk0;
          uint4 p0 = ((const uint4*)xp)[0];
          uint4 p1 = ((const uint4*)xp)[1];
          const unsigned short* pu = (const unsigned short*)&p0;
          #pragma unroll
          for (int q = 0; q < 8; q++) xs[kk0 + q][rr] = bf2f(pu[q]);
          pu = (const unsigned short*)&p1;
          #pragma unroll
          for (int q = 0; q < 8; q++) xs[kk0 + 8 + q][rr] = bf2f(pu[q]);
        }
      } else {
        #pragma unroll
        for (int q = 0; q < 16; q++) xs[kk0 + q][rr] = 0.f;
      }
    }
    __syncthreads();
    #pragma unroll 8
    for (int kk = 0; kk < 32; kk++) {
      float w0 = wlds[kc + kk][j0];
      float w1 = wlds[kc + kk][j0 + 1];
      const float4* xr = (const float4*)&xs[kk][r0];
      float4 xa = xr[0], xb = xr[1];
      float xv[8] = {xa.x, xa.y, xa.z, xa.w, xb.x, xb.y, xb.z, xb.w};
      #pragma unroll
      for (int i = 0; i < 8; i++) {
        acc[i][0] = fmaf(xv[i], w0, acc[i][0]);
        acc[i][1] = fmaf(xv[i], w1, acc[i][1]);
      }
    }
  }
  #pragma unroll
  for (int i = 0; i < 8; i++) {
    int grow = rb + r0 + i;
    if (grow < NN) {
      float2 v; v.x = acc[i][0]; v.y = acc[i][1];
      *((float2*)(h1 + (long long)grow * HID + j0)) = v;
    }
  }
}

// ---- gather1 fused: conv1 aggregate + self-loop + bias + ReLU + @W2 -> p2 ----
// 256 threads = 8 nodes x 32 lanes (lane = feature j)
// Edge loop unrolled x4: 4 independent csr->h1 load chains in flight.
__global__ __launch_bounds__(256) void gather1_kernel(const float* __restrict__ h1,
    const float* __restrict__ dinv, const int* __restrict__ rowptr,
    const int2* __restrict__ csr, const void* __restrict__ b1,
    const void* __restrict__ W2, float* __restrict__ p2,
    const int* __restrict__ flags) {
  __shared__ float w2lds[HID * OUTD];  // [k][m] flat
  __shared__ float b1l[HID];
  __shared__ float tl[8][HID + 1];
  int t = threadIdx.x;
  int isf32 = flags[1];
  w2lds[2 * t]     = ldf(W2, 2 * t, isf32);
  w2lds[2 * t + 1] = ldf(W2, 2 * t + 1, isf32);
  if (t < HID) b1l[t] = ldf(b1, t, isf32);
  __syncthreads();  // b1l/w2lds read by all threads below

  int nl = t >> 5;          // node slot 0..7
  int j  = t & 31;          // feature
  int node = blockIdx.x * 8 + nl;
  if (node < NN) {
    int k0 = rowptr[node], k1 = rowptr[node + 1];
    float acc = 0.f;
    int k = k0;
    for (; k + 4 <= k1; k += 4) {
      int2 q0 = csr[k];
      int2 q1 = csr[k + 1];
      int2 q2 = csr[k + 2];
      int2 q3 = csr[k + 3];
      float v0 = h1[q0.x * HID + j];
      float v1 = h1[q1.x * HID + j];
      float v2 = h1[q2.x * HID + j];
      float v3 = h1[q3.x * HID + j];
      acc = fmaf(__int_as_float(q0.y), v0, acc);
      acc = fmaf(__int_as_float(q1.y), v1, acc);
      acc = fmaf(__int_as_float(q2.y), v2, acc);
      acc = fmaf(__int_as_float(q3.y), v3, acc);
    }
    for (; k < k1; k++) {
      int2 pr = csr[k];
      acc = fmaf(__int_as_float(pr.y), h1[pr.x * HID + j], acc);
    }
    float di = dinv[node];
    acc = fmaf(di * di, h1[node * HID + j], acc);
    acc += b1l[j];
    tl[nl][j] = fmaxf(acc, 0.f);
  }
  __syncthreads();
  int m = t & 31;
  if (node < NN && m < OUTD) {
    float s = 0.f;
    #pragma unroll
    for (int k = 0; k < HID; k++) s = fmaf(tl[nl][k], w2lds[k * OUTD + m], s);
    p2[node * OUTD + m] = s;
  }
}

// ---- gather2: conv2 aggregate + self-loop + bias -> out ----
// 256 threads = 16 nodes x 16 lanes (lane = feature m); edge loop unrolled x4
__global__ __launch_bounds__(256) void gather2_kernel(const float* __restrict__ p2,
    const float* __restrict__ dinv, const int* __restrict__ rowptr,
    const int2* __restrict__ csr, const void* __restrict__ b2,
    void* __restrict__ out, const int* __restrict__ flags) {
  __shared__ float b2l[OUTD];
  int t = threadIdx.x;
  int isf32 = flags[1];
  if (t < OUTD) b2l[t] = ldf(b2, t, isf32);
  __syncthreads();

  int nl = t >> 4;
  int m  = t & 15;
  int node = blockIdx.x * 16 + nl;
  if (node >= NN) return;
  int k0 = rowptr[node], k1 = rowptr[node + 1];
  float acc = 0.f;
  int k = k0;
  for (; k + 4 <= k1; k += 4) {
    int2 q0 = csr[k];
    int2 q1 = csr[k + 1];
    int2 q2 = csr[k + 2];
    int2 q3 = csr[k + 3];
    float v0 = p2[q0.x * OUTD + m];
    float v1 = p2[q1.x * OUTD + m];
    float v2 = p2[q2.x * OUTD + m];
    float v3 = p2[q3.x * OUTD + m];
    acc = fmaf(__int_as_float(q0.y), v0, acc);
    acc = fmaf(__int_as_float(q1.y), v1, acc);
    acc = fmaf(__int_as_float(q2.y), v2, acc);
    acc = fmaf(__int_as_float(q3.y), v3, acc);
  }
  for (; k < k1; k++) {
    int2 pr = csr[k];
    acc = fmaf(__int_as_float(pr.y), p2[pr.x * OUTD + m], acc);
  }
  float di = dinv[node];
  acc = fmaf(di * di, p2[node * OUTD + m], acc);
  acc += b2l[m];
  int oidx = node * OUTD + m;
  if (isf32) ((float*)out)[oidx] = acc;
  else       ((unsigned short*)out)[oidx] = f2bf(acc);
}

extern "C" void kernel_launch(void* const* d_in, const int* in_sizes, int n_in,
                              void* d_out, int out_size, void* d_ws, size_t ws_size,
                              hipStream_t stream) {
  const void* x  = d_in[0];
  const int* ei  = (const int*)d_in[1];
  const void* ew = d_in[2];
  const void* W1 = d_in[3];
  const void* b1 = d_in[4];
  const void* W2 = d_in[5];
  const void* b2 = d_in[6];
  float* ws = (float*)d_ws;
  int* wsi = (int*)d_ws;
  unsigned long long* degpack = (unsigned long long*)(wsi + OFF_DEGPACK);

  detect_kernel<<<dim3(1), dim3(256), 0, stream>>>(ei, (const unsigned short*)x, wsi + OFF_FLAG);
  zero_kernel<<<dim3(512), dim3(256), 0, stream>>>(ws + OFF_DEGPACK, 2 * NN);  // degpack only
  count_rank_kernel<<<dim3((NE + 255) / 256), dim3(256), 0, stream>>>(ei, ew, degpack, wsi + OFF_RANK, wsi + OFF_FLAG);
  dinv_kernel<<<dim3(NBLK), dim3(256), 0, stream>>>(degpack, ws + OFF_DINV);
  scan_sum_kernel<<<dim3(NBLK), dim3(256), 0, stream>>>(degpack, wsi + OFF_BSUM);
  scan_offs_kernel<<<dim3(1), dim3(512), 0, stream>>>(wsi + OFF_BSUM, wsi + OFF_BOFF);
  scan_write_kernel<<<dim3(NBLK), dim3(256), 0, stream>>>(degpack, wsi + OFF_BOFF, wsi + OFF_ROWPTR);
  fill_csr_kernel<<<dim3((NE + 255) / 256), dim3(256), 0, stream>>>(ei, ew, ws + OFF_DINV, wsi + OFF_ROWPTR, wsi + OFF_RANK, (int2*)(wsi + OFF_CSR), wsi + OFF_FLAG);
  gemm1_kernel<<<dim3((NN + 127) / 128), dim3(256), 0, stream>>>(x, W1, ws + OFF_H1, wsi + OFF_FLAG);
  gather1_kernel<<<dim3((NN + 7) / 8), dim3(256), 0, stream>>>(ws + OFF_H1, ws + OFF_DINV, wsi + OFF_ROWPTR, (const int2*)(wsi + OFF_CSR), b1, W2, ws + OFF_P2, wsi + OFF_FLAG);
  gather2_kernel<<<dim3((NN + 15) / 16), dim3(256), 0, stream>>>(ws + OFF_P2, ws + OFF_DINV, wsi + OFF_ROWPTR, (const int2*)(wsi + OFF_CSR), b2, d_out, wsi + OFF_FLAG);
}

// Round 7
// 363.665 us; speedup vs baseline: 11.7227x; 1.1361x over previous
//
#include <hip/hip_runtime.h>
#include <hip/hip_bf16.h>

#define NN   100000
#define NE   1600000
#define FIN  256
#define HID  32
#define OUTD 16
#define NBLK ((NN + 255) / 256)   // 391 scan blocks
#define GEMM_BLOCKS ((NN + 127) / 128)      // 782
#define CNT_BLOCKS  ((NE + 255) / 256)      // 6250
#define FUSE_BLOCKS (GEMM_BLOCKS + CNT_BLOCKS)  // 7032

// ---- workspace layout (32-bit word offsets), total ~10.0M words = 40 MB ----
#define OFF_FLAG    0                      // [0]=is64, [1]=isf32
#define OFF_DEGPACK 64                     // NN u64 (2*NN words), 8B-aligned
#define OFF_DINV    (OFF_DEGPACK + 2*NN)   // NN floats
#define OFF_RANK    (OFF_DINV + NN)        // NE ints
#define OFF_BSUM    (OFF_RANK + NE)        // 512 ints
#define OFF_BOFF    (OFF_BSUM + 512)       // 512 ints
#define OFF_ROWPTR  (OFF_BOFF + 512)       // NN+1 ints
#define OFF_CSR     (OFF_ROWPTR + NN + 32) // 2*NE words (int2 pairs), 8B-aligned
#define OFF_H1      (OFF_CSR + 2*NE)       // NN*HID floats
#define OFF_P2      (OFF_H1 + NN*HID)      // NN*OUTD floats

#define PACK_SHIFT 40
#define PACK_MASK  ((1ull << PACK_SHIFT) - 1ull)
#define FP_SCALE   16777216.0f             // 2^24
#define FP_INV     (1.0f / 16777216.0f)

__device__ __forceinline__ float bf2f(unsigned short u) {
  union { unsigned int i; float f; } v; v.i = ((unsigned int)u) << 16; return v.f;
}
__device__ __forceinline__ unsigned short f2bf(float f) {
  union { float f; unsigned int i; } v; v.f = f;
  unsigned int x = v.i;
  return (unsigned short)((x + 0x7fffu + ((x >> 16) & 1u)) >> 16); // RNE
}
__device__ __forceinline__ int eidx(const int* __restrict__ ei, long long pos, int is64) {
  return is64 ? ei[2 * pos] : ei[pos];
}
__device__ __forceinline__ float ldf(const void* p, long long i, int isf32) {
  return isf32 ? ((const float*)p)[i] : bf2f(((const unsigned short*)p)[i]);
}

// ---- K0: detect flags (block 0) + zero degpack (blocks 1..) ----
__global__ __launch_bounds__(256) void detect_zero_kernel(const int* __restrict__ ei,
    const unsigned short* __restrict__ xu, int* __restrict__ flags,
    float* __restrict__ zp, int zn) {
  int b = blockIdx.x;
  if (b == 0) {
    __shared__ int any, cnt;
    if (threadIdx.x == 0) { any = 0; cnt = 0; }
    __syncthreads();
    int local = 0, c = 0;
    for (int i = threadIdx.x; i < 2048; i += 256) local |= ei[2 * i + 1];
    for (int i = threadIdx.x; i < 1024; i += 256) {
      unsigned int e = (xu[2 * i] >> 7) & 0xFF;
      c += (e < 100 || e > 140) ? 1 : 0;
    }
    if (local) atomicOr(&any, 1);
    atomicAdd(&cnt, c);
    __syncthreads();
    if (threadIdx.x == 0) {
      flags[0] = (any == 0) ? 1 : 0;   // 1 => int64 layout
      flags[1] = (cnt > 100) ? 1 : 0;  // 1 => f32 floats
    }
  } else {
    int stride = (gridDim.x - 1) * 256;
    for (int i = (b - 1) * 256 + threadIdx.x; i < zn; i += stride) zp[i] = 0.f;
  }
}

// ---- K1 FUSED: count_rank (atomic-bound) + gemm1 (VALU/HBM-bound) ----
// Every 9th block (b%9==0, b/9<782) is a gemm block; the rest are count blocks.
// Interleave keeps each CU holding a mix -> atomic pipe and VALU pipe overlap.
__global__ __launch_bounds__(256) void count_gemm_kernel(const int* __restrict__ ei,
    const void* __restrict__ ew, unsigned long long* __restrict__ degpack,
    int* __restrict__ rank, const void* __restrict__ x,
    const void* __restrict__ W1, float* __restrict__ h1,
    const int* __restrict__ flags) {
  __shared__ float wlds[FIN][HID];   // 32 KB (allocated for all blocks; occupancy 3/CU)
  __shared__ float xs[32][132];      // 16.5 KB
  int b = blockIdx.x;
  int t = threadIdx.x;
  bool is_gemm = ((b % 9) == 0) && (b / 9) < GEMM_BLOCKS;

  if (!is_gemm) {
    // ---- count_rank body ----
    int cid = b - 1 - b / 9;               // bijective onto 0..CNT_BLOCKS-1
    int e = cid * 256 + t;
    if (e >= NE) return;
    int c = eidx(ei, (long long)NE + e, flags[0]);
    float w = ldf(ew, e, flags[1]);
    unsigned long long inc = (1ull << PACK_SHIFT)
                           | (unsigned long long)(w * FP_SCALE + 0.5f);
    unsigned long long old = atomicAdd(degpack + c, inc);
    rank[e] = (int)(old >> PACK_SHIFT);
    return;
  }

  // ---- gemm1 body: h1 = x @ W1 ----
  int rb = (b / 9) * 128;
  int isf32 = flags[1];

  if (isf32) {
    const float* wrow = (const float*)W1 + t * HID;
    #pragma unroll
    for (int jj = 0; jj < HID; jj += 4)
      *(float4*)&wlds[t][jj] = *((const float4*)(wrow + jj));
  } else {
    const unsigned short* wrow = (const unsigned short*)W1 + t * HID;
    #pragma unroll
    for (int jj = 0; jj < HID; jj += 8) {
      uint4 pk = *((const uint4*)(wrow + jj));
      const unsigned short* pu = (const unsigned short*)&pk;
      #pragma unroll
      for (int q = 0; q < 8; q++) wlds[t][jj + q] = bf2f(pu[q]);
    }
  }

  int j0 = (t & 15) * 2;
  int r0 = (t >> 4) * 8;
  float acc[8][2];
  #pragma unroll
  for (int i = 0; i < 8; i++) { acc[i][0] = 0.f; acc[i][1] = 0.f; }

  for (int kc = 0; kc < FIN; kc += 32) {
    __syncthreads();
    {
      int rr = t >> 1;
      int kk0 = (t & 1) * 16;
      int grow = rb + rr;
      if (grow < NN) {
        if (isf32) {
          const float* xp = (const float*)x + (long long)grow * FIN + kc + kk0;
          #pragma unroll
          for (int q4 = 0; q4 < 4; q4++) {
            float4 p = ((const float4*)xp)[q4];
            xs[kk0 + q4 * 4 + 0][rr] = p.x;
            xs[kk0 + q4 * 4 + 1][rr] = p.y;
            xs[kk0 + q4 * 4 + 2][rr] = p.z;
            xs[kk0 + q4 * 4 + 3][rr] = p.w;
          }
        } else {
          const unsigned short* xp = (const unsigned short*)x + (long long)grow * FIN + kc + kk0;
          uint4 p0 = ((const uint4*)xp)[0];
          uint4 p1 = ((const uint4*)xp)[1];
          const unsigned short* pu = (const unsigned short*)&p0;
          #pragma unroll
          for (int q = 0; q < 8; q++) xs[kk0 + q][rr] = bf2f(pu[q]);
          pu = (const unsigned short*)&p1;
          #pragma unroll
          for (int q = 0; q < 8; q++) xs[kk0 + 8 + q][rr] = bf2f(pu[q]);
        }
      } else {
        #pragma unroll
        for (int q = 0; q < 16; q++) xs[kk0 + q][rr] = 0.f;
      }
    }
    __syncthreads();
    #pragma unroll 8
    for (int kk = 0; kk < 32; kk++) {
      float w0 = wlds[kc + kk][j0];
      float w1 = wlds[kc + kk][j0 + 1];
      const float4* xr = (const float4*)&xs[kk][r0];
      float4 xa = xr[0], xb = xr[1];
      float xv[8] = {xa.x, xa.y, xa.z, xa.w, xb.x, xb.y, xb.z, xb.w};
      #pragma unroll
      for (int i = 0; i < 8; i++) {
        acc[i][0] = fmaf(xv[i], w0, acc[i][0]);
        acc[i][1] = fmaf(xv[i], w1, acc[i][1]);
      }
    }
  }
  #pragma unroll
  for (int i = 0; i < 8; i++) {
    int grow = rb + r0 + i;
    if (grow < NN) {
      float2 v; v.x = acc[i][0]; v.y = acc[i][1];
      *((float2*)(h1 + (long long)grow * HID + j0)) = v;
    }
  }
}

// ---- K2 FUSED: scan_sum (blocks 0..390) + dinv (blocks 391..781) ----
__global__ __launch_bounds__(256) void dinv_scansum_kernel(
    const unsigned long long* __restrict__ degpack, float* __restrict__ dinv,
    int* __restrict__ bsum) {
  int b = blockIdx.x;
  if (b < NBLK) {
    __shared__ int s[256];
    int i = b * 256 + threadIdx.x;
    s[threadIdx.x] = (i < NN) ? (int)(degpack[i] >> PACK_SHIFT) : 0;
    __syncthreads();
    for (int off = 128; off > 0; off >>= 1) {
      if (threadIdx.x < off) s[threadIdx.x] += s[threadIdx.x + off];
      __syncthreads();
    }
    if (threadIdx.x == 0) bsum[b] = s[0];
  } else {
    int i = (b - NBLK) * 256 + threadIdx.x;
    if (i >= NN) return;
    float d = (float)(degpack[i] & PACK_MASK) * FP_INV + 1.0f;  // + self-loop
    dinv[i] = (d > 0.f) ? rsqrtf(d) : 0.f;
  }
}

// ---- scan k2: exclusive scan of block sums (single block, 512 thr) ----
__global__ __launch_bounds__(512) void scan_offs_kernel(const int* __restrict__ bsum,
                                                        int* __restrict__ boff) {
  __shared__ int a[512];
  int t = threadIdx.x;
  int orig = (t < NBLK) ? bsum[t] : 0;
  a[t] = orig;
  __syncthreads();
  for (int off = 1; off < 512; off <<= 1) {
    int v = a[t] + ((t >= off) ? a[t - off] : 0);
    __syncthreads();
    a[t] = v;
    __syncthreads();
  }
  if (t < NBLK) boff[t] = a[t] - orig;   // exclusive
}

// ---- scan k3: write rowptr ----
__global__ __launch_bounds__(256) void scan_write_kernel(const unsigned long long* __restrict__ degpack,
    const int* __restrict__ boff, int* __restrict__ rowptr) {
  __shared__ int a[256];
  int t = threadIdx.x;
  int i = blockIdx.x * 256 + t;
  int orig = (i < NN) ? (int)(degpack[i] >> PACK_SHIFT) : 0;
  a[t] = orig;
  __syncthreads();
  for (int off = 1; off < 256; off <<= 1) {
    int v = a[t] + ((t >= off) ? a[t - off] : 0);
    __syncthreads();
    a[t] = v;
    __syncthreads();
  }
  if (i < NN) rowptr[i] = boff[blockIdx.x] + a[t] - orig;  // exclusive
  if (blockIdx.x == 0 && t == 0) rowptr[NN] = NE;
}

// ---- fill CSR: (src, norm) pairs bucketed by dst — NO atomics ----
__global__ __launch_bounds__(256) void fill_csr_kernel(const int* __restrict__ ei,
    const void* __restrict__ ew, const float* __restrict__ dinv,
    const int* __restrict__ rowptr, const int* __restrict__ rank,
    int2* __restrict__ csr, const int* __restrict__ flags) {
  int e = blockIdx.x * 256 + threadIdx.x;
  if (e >= NE) return;
  int is64 = flags[0];
  int r = eidx(ei, e, is64);
  int c = eidx(ei, (long long)NE + e, is64);
  float nw = dinv[r] * ldf(ew, e, flags[1]) * dinv[c];
  int pos = rowptr[c] + rank[e];
  int2 pr; pr.x = r; pr.y = __float_as_int(nw);
  csr[pos] = pr;
}

// ---- gather1 fused: conv1 aggregate + self-loop + bias + ReLU + @W2 -> p2 ----
// 256 threads = 8 nodes x 32 lanes; edge loop unrolled x8 (8 chains in flight)
__global__ __launch_bounds__(256) void gather1_kernel(const float* __restrict__ h1,
    const float* __restrict__ dinv, const int* __restrict__ rowptr,
    const int2* __restrict__ csr, const void* __restrict__ b1,
    const void* __restrict__ W2, float* __restrict__ p2,
    const int* __restrict__ flags) {
  __shared__ float w2lds[HID * OUTD];  // [k][m] flat
  __shared__ float b1l[HID];
  __shared__ float tl[8][HID + 1];
  int t = threadIdx.x;
  int isf32 = flags[1];
  w2lds[2 * t]     = ldf(W2, 2 * t, isf32);
  w2lds[2 * t + 1] = ldf(W2, 2 * t + 1, isf32);
  if (t < HID) b1l[t] = ldf(b1, t, isf32);
  __syncthreads();  // b1l/w2lds read by all threads below

  int nl = t >> 5;          // node slot 0..7
  int j  = t & 31;          // feature
  int node = blockIdx.x * 8 + nl;
  if (node < NN) {
    int k0 = rowptr[node], k1 = rowptr[node + 1];
    float acc = 0.f;
    int k = k0;
    for (; k + 8 <= k1; k += 8) {
      int2 q0 = csr[k];     int2 q1 = csr[k + 1];
      int2 q2 = csr[k + 2]; int2 q3 = csr[k + 3];
      int2 q4 = csr[k + 4]; int2 q5 = csr[k + 5];
      int2 q6 = csr[k + 6]; int2 q7 = csr[k + 7];
      float v0 = h1[q0.x * HID + j]; float v1 = h1[q1.x * HID + j];
      float v2 = h1[q2.x * HID + j]; float v3 = h1[q3.x * HID + j];
      float v4 = h1[q4.x * HID + j]; float v5 = h1[q5.x * HID + j];
      float v6 = h1[q6.x * HID + j]; float v7 = h1[q7.x * HID + j];
      acc = fmaf(__int_as_float(q0.y), v0, acc);
      acc = fmaf(__int_as_float(q1.y), v1, acc);
      acc = fmaf(__int_as_float(q2.y), v2, acc);
      acc = fmaf(__int_as_float(q3.y), v3, acc);
      acc = fmaf(__int_as_float(q4.y), v4, acc);
      acc = fmaf(__int_as_float(q5.y), v5, acc);
      acc = fmaf(__int_as_float(q6.y), v6, acc);
      acc = fmaf(__int_as_float(q7.y), v7, acc);
    }
    for (; k + 4 <= k1; k += 4) {
      int2 q0 = csr[k];     int2 q1 = csr[k + 1];
      int2 q2 = csr[k + 2]; int2 q3 = csr[k + 3];
      float v0 = h1[q0.x * HID + j]; float v1 = h1[q1.x * HID + j];
      float v2 = h1[q2.x * HID + j]; float v3 = h1[q3.x * HID + j];
      acc = fmaf(__int_as_float(q0.y), v0, acc);
      acc = fmaf(__int_as_float(q1.y), v1, acc);
      acc = fmaf(__int_as_float(q2.y), v2, acc);
      acc = fmaf(__int_as_float(q3.y), v3, acc);
    }
    for (; k < k1; k++) {
      int2 pr = csr[k];
      acc = fmaf(__int_as_float(pr.y), h1[pr.x * HID + j], acc);
    }
    float di = dinv[node];
    acc = fmaf(di * di, h1[node * HID + j], acc);
    acc += b1l[j];
    tl[nl][j] = fmaxf(acc, 0.f);
  }
  __syncthreads();
  int m = t & 31;
  if (node < NN && m < OUTD) {
    float s = 0.f;
    #pragma unroll
    for (int k = 0; k < HID; k++) s = fmaf(tl[nl][k], w2lds[k * OUTD + m], s);
    p2[node * OUTD + m] = s;
  }
}

// ---- gather2: conv2 aggregate + self-loop + bias -> out ----
// 256 threads = 16 nodes x 16 lanes; edge loop unrolled x8
__global__ __launch_bounds__(256) void gather2_kernel(const float* __restrict__ p2,
    const float* __restrict__ dinv, const int* __restrict__ rowptr,
    const int2* __restrict__ csr, const void* __restrict__ b2,
    void* __restrict__ out, const int* __restrict__ flags) {
  __shared__ float b2l[OUTD];
  int t = threadIdx.x;
  int isf32 = flags[1];
  if (t < OUTD) b2l[t] = ldf(b2, t, isf32);
  __syncthreads();

  int nl = t >> 4;
  int m  = t & 15;
  int node = blockIdx.x * 16 + nl;
  if (node >= NN) return;
  int k0 = rowptr[node], k1 = rowptr[node + 1];
  float acc = 0.f;
  int k = k0;
  for (; k + 8 <= k1; k += 8) {
    int2 q0 = csr[k];     int2 q1 = csr[k + 1];
    int2 q2 = csr[k + 2]; int2 q3 = csr[k + 3];
    int2 q4 = csr[k + 4]; int2 q5 = csr[k + 5];
    int2 q6 = csr[k + 6]; int2 q7 = csr[k + 7];
    float v0 = p2[q0.x * OUTD + m]; float v1 = p2[q1.x * OUTD + m];
    float v2 = p2[q2.x * OUTD + m]; float v3 = p2[q3.x * OUTD + m];
    float v4 = p2[q4.x * OUTD + m]; float v5 = p2[q5.x * OUTD + m];
    float v6 = p2[q6.x * OUTD + m]; float v7 = p2[q7.x * OUTD + m];
    acc = fmaf(__int_as_float(q0.y), v0, acc);
    acc = fmaf(__int_as_float(q1.y), v1, acc);
    acc = fmaf(__int_as_float(q2.y), v2, acc);
    acc = fmaf(__int_as_float(q3.y), v3, acc);
    acc = fmaf(__int_as_float(q4.y), v4, acc);
    acc = fmaf(__int_as_float(q5.y), v5, acc);
    acc = fmaf(__int_as_float(q6.y), v6, acc);
    acc = fmaf(__int_as_float(q7.y), v7, acc);
  }
  for (; k + 4 <= k1; k += 4) {
    int2 q0 = csr[k];     int2 q1 = csr[k + 1];
    int2 q2 = csr[k + 2]; int2 q3 = csr[k + 3];
    float v0 = p2[q0.x * OUTD + m]; float v1 = p2[q1.x * OUTD + m];
    float v2 = p2[q2.x * OUTD + m]; float v3 = p2[q3.x * OUTD + m];
    acc = fmaf(__int_as_float(q0.y), v0, acc);
    acc = fmaf(__int_as_float(q1.y), v1, acc);
    acc = fmaf(__int_as_float(q2.y), v2, acc);
    acc = fmaf(__int_as_float(q3.y), v3, acc);
  }
  for (; k < k1; k++) {
    int2 pr = csr[k];
    acc = fmaf(__int_as_float(pr.y), p2[pr.x * OUTD + m], acc);
  }
  float di = dinv[node];
  acc = fmaf(di * di, p2[node * OUTD + m], acc);
  acc += b2l[m];
  int oidx = node * OUTD + m;
  if (isf32) ((float*)out)[oidx] = acc;
  else       ((unsigned short*)out)[oidx] = f2bf(acc);
}

extern "C" void kernel_launch(void* const* d_in, const int* in_sizes, int n_in,
                              void* d_out, int out_size, void* d_ws, size_t ws_size,
                              hipStream_t stream) {
  const void* x  = d_in[0];
  const int* ei  = (const int*)d_in[1];
  const void* ew = d_in[2];
  const void* W1 = d_in[3];
  const void* b1 = d_in[4];
  const void* W2 = d_in[5];
  const void* b2 = d_in[6];
  float* ws = (float*)d_ws;
  int* wsi = (int*)d_ws;
  unsigned long long* degpack = (unsigned long long*)(wsi + OFF_DEGPACK);

  detect_zero_kernel<<<dim3(513), dim3(256), 0, stream>>>(ei, (const unsigned short*)x,
      wsi + OFF_FLAG, ws + OFF_DEGPACK, 2 * NN);
  count_gemm_kernel<<<dim3(FUSE_BLOCKS), dim3(256), 0, stream>>>(ei, ew, degpack,
      wsi + OFF_RANK, x, W1, ws + OFF_H1, wsi + OFF_FLAG);
  dinv_scansum_kernel<<<dim3(2 * NBLK), dim3(256), 0, stream>>>(degpack, ws + OFF_DINV, wsi + OFF_BSUM);
  scan_offs_kernel<<<dim3(1), dim3(512), 0, stream>>>(wsi + OFF_BSUM, wsi + OFF_BOFF);
  scan_write_kernel<<<dim3(NBLK), dim3(256), 0, stream>>>(degpack, wsi + OFF_BOFF, wsi + OFF_ROWPTR);
  fill_csr_kernel<<<dim3((NE + 255) / 256), dim3(256), 0, stream>>>(ei, ew, ws + OFF_DINV, wsi + OFF_ROWPTR, wsi + OFF_RANK, (int2*)(wsi + OFF_CSR), wsi + OFF_FLAG);
  gather1_kernel<<<dim3((NN + 7) / 8), dim3(256), 0, stream>>>(ws + OFF_H1, ws + OFF_DINV, wsi + OFF_ROWPTR, (const int2*)(wsi + OFF_CSR), b1, W2, ws + OFF_P2, wsi + OFF_FLAG);
  gather2_kernel<<<dim3((NN + 15) / 16), dim3(256), 0, stream>>>(ws + OFF_P2, ws + OFF_DINV, wsi + OFF_ROWPTR, (const int2*)(wsi + OFF_CSR), b2, d_out, wsi + OFF_FLAG);
}